// Round 3
// baseline (1728.118 us; speedup 1.0000x reference)
//
#include <hip/hip_runtime.h>
#include <cmath>

#define NB 8
#define NT 2048
#define NV 4096
#define NK 12          // top-K p values kept per row (candidate margin over 8)

__device__ __forceinline__ void lds_fence() {
  asm volatile("s_waitcnt lgkmcnt(0)" ::: "memory");
}

// ---------------------------------------------------------------------------
// Kernel A: per-row (b,t): M = max(x) (exact f32), L = log(sum(exp(x-M))) in
// f64, logP = fl32(fl32(x - M) - fl32(L)) (mimics the np f32 port's rounding
// structure), plus top-12 of the f32 logP row (value desc, index asc).
// One wave per row.
// ---------------------------------------------------------------------------
__global__ __launch_bounds__(64) void lsm_top12_kernel(
    const float* __restrict__ logits,
    float* __restrict__ out_logP,
    float* __restrict__ topPf,
    int* __restrict__ topI)
{
  const int row  = blockIdx.x;           // b*NT + t
  const int lane = threadIdx.x;          // 0..63
  const float4* __restrict__ x4 = (const float4*)(logits + (size_t)row * NV);

  // ---- pass 1: exact f32 row max ----
  float m = -INFINITY;
  #pragma unroll 1
  for (int k = 0; k < 16; ++k) {
    float4 f = x4[lane + (k << 6)];
    m = fmaxf(m, fmaxf(fmaxf(f.x, f.y), fmaxf(f.z, f.w)));
  }
  #pragma unroll
  for (int off = 32; off > 0; off >>= 1) m = fmaxf(m, __shfl_xor(m, off, 64));

  // ---- pass 2: f64 sum of exp (xor-butterfly: identical bits in all lanes) --
  const double md = (double)m;
  double acc = 0.0;
  #pragma unroll 1
  for (int k = 0; k < 16; ++k) {
    float4 f = x4[lane + (k << 6)];
    acc += exp((double)f.x - md);
    acc += exp((double)f.y - md);
    acc += exp((double)f.z - md);
    acc += exp((double)f.w - md);
  }
  #pragma unroll
  for (int off = 32; off > 0; off >>= 1) acc += __shfl_xor(acc, off, 64);
  const float L32 = (float)log(acc);

  // ---- pass 3: f32 logP + lane-local top-12 (value desc, idx asc) ----
  float lv[NK]; int li[NK];
  #pragma unroll
  for (int z = 0; z < NK; ++z) { lv[z] = -INFINITY; li[z] = 0x7FFFFFFF; }

  // strict > on value keeps earlier (lower) index among equals => stable
#define INS(VAL, IDX)                                                       \
  do {                                                                      \
    float _v = (VAL); int _i = (IDX);                                       \
    if (_v > lv[NK - 1]) {                                                  \
      lv[NK - 1] = _v; li[NK - 1] = _i;                                     \
      for (int z = NK - 1; z > 0; --z)                                      \
        if (lv[z] > lv[z - 1]) {                                            \
          float tv = lv[z]; lv[z] = lv[z - 1]; lv[z - 1] = tv;              \
          int   ti = li[z]; li[z] = li[z - 1]; li[z - 1] = ti;              \
        }                                                                   \
    }                                                                       \
  } while (0)

  float4* __restrict__ orow4 = (float4*)(out_logP + (size_t)row * NV);
  #pragma unroll 1
  for (int k = 0; k < 16; ++k) {
    float4 f = x4[lane + (k << 6)];
    int vb = (lane + (k << 6)) << 2;
    float4 o;
    o.x = (f.x - m) - L32;
    o.y = (f.y - m) - L32;
    o.z = (f.z - m) - L32;
    o.w = (f.w - m) - L32;
    orow4[lane + (k << 6)] = o;
    INS(o.x, vb); INS(o.y, vb + 1); INS(o.z, vb + 2); INS(o.w, vb + 3);
  }
#undef INS

  // ---- wave merge: 12 rounds of butterfly argmax (value desc, idx asc) ----
  float mv = 0.0f; int mi = 0;
  #pragma unroll
  for (int r = 0; r < NK; ++r) {
    float cv = lv[0]; int ci = li[0];
    #pragma unroll
    for (int off = 32; off > 0; off >>= 1) {
      float ov = __shfl_xor(cv, off, 64);
      int   oi = __shfl_xor(ci, off, 64);
      if (ov > cv || (ov == cv && oi < ci)) { cv = ov; ci = oi; }
    }
    if (r == 0)    { mv = cv; mi = ci; }
    if (lane == r) { mv = cv; mi = ci; }
    if (lv[0] == cv && li[0] == ci) {   // unique owner pops its head
      for (int z = 0; z < NK - 1; ++z) { lv[z] = lv[z + 1]; li[z] = li[z + 1]; }
      lv[NK - 1] = -INFINITY; li[NK - 1] = 0x7FFFFFFF;
    }
  }
  if (lane < NK) {
    topPf[(size_t)row * NK + lane] = mv;
    topI [(size_t)row * NK + lane] = mi;
  }
}

// ---------------------------------------------------------------------------
// Kernel B: f32 beam search + backtrace + CTC collapse. One wave per batch.
// 31 active lanes hold candidates (i,j) with (i+1)(j+1) <= 12.
// ---------------------------------------------------------------------------
__global__ __launch_bounds__(64) void beam_kernel(
    const float* __restrict__ topPf,
    const int* __restrict__ topI,
    const int* __restrict__ lengths,
    float* __restrict__ out_tok,
    float* __restrict__ out_lenA,
    float* __restrict__ out_scr)
{
  const int b    = blockIdx.x;
  const int lane = threadIdx.x;

  __shared__ unsigned short tokbp[NT * 8];   // (v<<3)|bp per (t, rank)
  __shared__ unsigned short pathA[NT];
  __shared__ float nb_s[8];

  int len = lengths[b];
  if (len < 1) len = 1;
  if (len > NT) len = NT;

  // lane -> (i,j) over all (i+1)(j+1) <= 12  (counts 12,6,4,3,2,2,1,1 = 31)
  int i_l = 0, j_l = 0; bool active = false;
  {
    int c = 0;
    #pragma unroll
    for (int i = 0; i < 8; ++i) {
      const int cnt = 12 / (i + 1);          // floor
      if (lane >= c && lane < c + cnt) { i_l = i; j_l = lane - c; active = true; }
      c += cnt;
    }
  }

  const float* __restrict__ Pb = topPf + (size_t)b * NT * NK;
  const int*   __restrict__ Ib = topI  + (size_t)b * NT * NK;

  // t = 0: beams = row-0 top-8 (sorted desc, idx-asc ties)
  float s = Pb[i_l < 8 ? i_l : 0];
  if (lane < 8) tokbp[lane] = (unsigned short)(Ib[lane] << 3);   // bp = 0

  float p_cur = Pb[NK + j_l];     // t = 1 (len >= 1024 so row 1 exists)
  int   v_cur = Ib[NK + j_l];

  for (int t = 1; t < len; ++t) {
    const int tn = (t + 1 < len) ? (t + 1) : t;
    const float p_nxt = Pb[(size_t)tn * NK + j_l];
    const int   v_nxt = Ib[(size_t)tn * NK + j_l];

    const float cand = s + p_cur;            // single f32 add, matches np

    // sortable key: (f32 value asc-mapped to u32) << 15 | (0x7FFF - flat)
    unsigned int cb = __float_as_uint(cand);
    cb ^= (unsigned int)((int)cb >> 31) | 0x80000000u;
    const unsigned int flat = (unsigned int)((i_l << 12) | v_cur);
    unsigned long long key =
        ((unsigned long long)cb << 15) | (unsigned long long)(0x7FFFu ^ flat);
    if (!active) key = 0ULL;

    const unsigned int klo = (unsigned int)key;
    const unsigned int khi = (unsigned int)(key >> 32);

    int rank = 0;
    #pragma unroll
    for (int mm = 0; mm < 31; ++mm) {
      unsigned int olo = (unsigned int)__builtin_amdgcn_readlane((int)klo, mm);
      unsigned int ohi = (unsigned int)__builtin_amdgcn_readlane((int)khi, mm);
      unsigned long long ok = ((unsigned long long)ohi << 32) | olo;
      rank += (ok > key) ? 1 : 0;
    }

    if (active && rank < 8) {                // exactly 8 winners (keys unique)
      nb_s[rank] = cand;
      tokbp[t * 8 + rank] = (unsigned short)((v_cur << 3) | i_l);
    }
    lds_fence();
    s = nb_s[i_l < 8 ? i_l : 0];

    p_cur = p_nxt; v_cur = v_nxt;
  }

  // ---- backtrace best beam (beam 0) ----
  lds_fence();
  if (lane == 0) {
    int beam = 0;
    for (int t = len - 1; t >= 0; --t) {
      int e = tokbp[t * 8 + beam];
      pathA[t] = (unsigned short)(e >> 3);
      beam = e & 7;
    }
  }
  lds_fence();

  // ---- CTC collapse: drop blanks & consecutive repeats, t < len ----
  const int CH = NT / 64;          // 32 contiguous t per lane
  const int base = lane * CH;
  int cnt = 0;
  for (int k = 0; k < CH; ++k) {
    int t = base + k;
    if (t < len) {
      int pt = pathA[t];
      int pv = (t > 0) ? (int)pathA[t - 1] : -1;
      cnt += ((pt != 0) && (pt != pv)) ? 1 : 0;
    }
  }
  int incl = cnt;
  #pragma unroll
  for (int off = 1; off < 64; off <<= 1) {
    int n = __shfl_up(incl, off, 64);
    if (lane >= off) incl += n;
  }
  const int excl  = incl - cnt;
  const int total = __shfl(incl, 63, 64);

  float* __restrict__ ob = out_tok + (size_t)b * NT;
  int pos = excl;
  for (int k = 0; k < CH; ++k) {
    int t = base + k;
    if (t < len) {
      int pt = pathA[t];
      int pv = (t > 0) ? (int)pathA[t - 1] : -1;
      if ((pt != 0) && (pt != pv)) { ob[pos] = (float)pt; ++pos; }
    }
  }
  for (int q = total + lane; q < NT; q += 64) ob[q] = -1.0f;

  if (lane == 0) {
    out_lenA[b] = (float)total;
    out_scr[b]  = s;               // lane 0 == beam 0
  }
}

// ---------------------------------------------------------------------------
extern "C" void kernel_launch(void* const* d_in, const int* in_sizes, int n_in,
                              void* d_out, int out_size, void* d_ws, size_t ws_size,
                              hipStream_t stream) {
  (void)in_sizes; (void)n_in; (void)out_size; (void)ws_size;
  const float* logits  = (const float*)d_in[0];
  const int*   lengths = (const int*)d_in[1];

  float* out_tok  = (float*)d_out;                 // B*T tokens (as float)
  float* out_lenp = out_tok + NB * NT;             // B out_lens
  float* out_scr  = out_lenp + NB;                 // B best_scores
  float* out_logP = out_scr + NB;                  // B*T*V logP

  float* topPf = (float*)d_ws;                     // 16384*12 f32 = 768 KiB
  int*   topI  = (int*)(topPf + (size_t)NB * NT * NK); // 768 KiB

  lsm_top12_kernel<<<NB * NT, 64, 0, stream>>>(logits, out_logP, topPf, topI);
  beam_kernel<<<NB, 64, 0, stream>>>(topPf, topI, lengths, out_tok, out_lenp, out_scr);
}